// Round 1
// baseline (883.778 us; speedup 1.0000x reference)
//
#include <hip/hip_runtime.h>
#include <hip/hip_bf16.h>

// out[r, f] = bias[f] + sum_{i: rows[i]==r} value[i] * weight[cols[i], f]
// N_NODES=100000, IN_FEATURES=5000, OUT=64, NNZ=4000000.
// Inputs: d_in[0]=index int32 [2,nnz], d_in[1]=value f32 [nnz], d_in[2]=n (scalar int),
//         d_in[3]=weight f32 [5000,64], d_in[4]=bias f32 [64]. Output f32 [n,64].

#define OUTF 64

// Kernel 1: out[r*64+f] = bias[f]  (must fully init: harness poisons d_out each launch)
__global__ void sl_init_bias(const float* __restrict__ bias, float4* __restrict__ out4,
                             int total4) {
    int idx = blockIdx.x * blockDim.x + threadIdx.x;
    if (idx >= total4) return;
    // 64 floats per row = 16 float4 per row; column within row = idx & 15
    const float4* b4 = (const float4*)bias;
    out4[idx] = b4[idx & 15];
}

// Kernel 2: one 64-lane wave processes 64 nnz. Lanes load 64 (row,col,val)
// coalesced, then broadcast each via shfl; lane f handles feature f.
__global__ void sl_scatter(const int* __restrict__ rows, const int* __restrict__ cols,
                           const float* __restrict__ vals, const float* __restrict__ weight,
                           float* __restrict__ out, int nnz) {
    int lane = threadIdx.x & 63;
    int wave = (blockIdx.x * (blockDim.x >> 6)) + (threadIdx.x >> 6);
    long long base = (long long)wave * 64;
    if (base >= nnz) return;

    int i = (int)base + lane;
    int r = 0, c = 0;
    float v = 0.0f;
    if (i < nnz) {
        r = rows[i];
        c = cols[i];
        v = vals[i];
    }
    int cnt = (int)min((long long)64, (long long)nnz - base);

    #pragma unroll 4
    for (int j = 0; j < cnt; ++j) {
        int   rj = __shfl(r, j);
        int   cj = __shfl(c, j);
        float vj = __shfl(v, j);
        float w  = weight[cj * OUTF + lane];
        atomicAdd(&out[(long long)rj * OUTF + lane], vj * w);
    }
}

extern "C" void kernel_launch(void* const* d_in, const int* in_sizes, int n_in,
                              void* d_out, int out_size, void* d_ws, size_t ws_size,
                              hipStream_t stream) {
    const int*   index  = (const int*)d_in[0];
    const float* value  = (const float*)d_in[1];
    const float* weight = (const float*)d_in[3];
    const float* bias   = (const float*)d_in[4];
    float*       out    = (float*)d_out;

    int nnz = in_sizes[0] / 2;
    const int* rows = index;
    const int* cols = index + nnz;

    // 1) init output with bias
    int total4 = out_size / 4;  // float4 count
    int ib = (total4 + 255) / 256;
    sl_init_bias<<<ib, 256, 0, stream>>>(bias, (float4*)out, total4);

    // 2) atomic scatter-add, one wave per 64 nnz, 4 waves/block
    int waves  = (nnz + 63) / 64;
    int blocks = (waves + 3) / 4;
    sl_scatter<<<blocks, 256, 0, stream>>>(rows, cols, value, weight, out, nnz);
}

// Round 2
// 682.386 us; speedup vs baseline: 1.2951x; 1.2951x over previous
//
#include <hip/hip_runtime.h>
#include <hip/hip_bf16.h>

// out[r,f] = bias[f] + sum_{i: rows[i]==r} value[i] * weight[cols[i], f]
// Strategy: build CSR in workspace (histogram -> scan -> scatter), then one
// wave per row does a gather + FMA and a single coalesced store (no output
// atomics). Round 0 showed 1.0 GB of atomic write-through traffic @1.3 TB/s.
//
// ws layout: [0, 512K): row counters / starts / (after scatter) ends  (n ints)
//            [512K, 516K): block sums for scan (<=1024 ints)
//            [1M, 1M+8*nnz): (col,val) pairs sorted by row           (32 MB)

#define OUTF 64
#define SCAN_B 512

__global__ void k_zero(int* __restrict__ p, int n) {
    int i = blockIdx.x * blockDim.x + threadIdx.x;
    if (i < n) p[i] = 0;
}

__global__ void k_hist(const int* __restrict__ rows, int* __restrict__ cnt, int nnz) {
    int i = blockIdx.x * blockDim.x + threadIdx.x;
    if (i < nnz) atomicAdd(&cnt[rows[i]], 1);
}

// Per-block exclusive scan; writes per-element exclusive prefix and block total.
__global__ void k_scan1(const int* __restrict__ in, int* __restrict__ out,
                        int* __restrict__ blockSums, int n) {
    __shared__ int s[SCAN_B];
    int t = threadIdx.x;
    int i = blockIdx.x * SCAN_B + t;
    int v = (i < n) ? in[i] : 0;
    s[t] = v;
    __syncthreads();
    for (int off = 1; off < SCAN_B; off <<= 1) {
        int x = (t >= off) ? s[t - off] : 0;
        __syncthreads();
        s[t] += x;
        __syncthreads();
    }
    if (i < n) out[i] = s[t] - v;  // exclusive
    if (t == SCAN_B - 1) blockSums[blockIdx.x] = s[t];
}

// Single-block exclusive scan of block sums (numBlocks <= 1024).
__global__ void k_scan2(int* __restrict__ blockSums, int numBlocks) {
    __shared__ int s[1024];
    int t = threadIdx.x;
    int v = (t < numBlocks) ? blockSums[t] : 0;
    s[t] = v;
    __syncthreads();
    for (int off = 1; off < 1024; off <<= 1) {
        int x = (t >= off) ? s[t - off] : 0;
        __syncthreads();
        s[t] += x;
        __syncthreads();
    }
    if (t < numBlocks) blockSums[t] = s[t] - v;  // exclusive
}

__global__ void k_scan3(int* __restrict__ data, const int* __restrict__ blockSums, int n) {
    int i = blockIdx.x * SCAN_B + threadIdx.x;
    if (i < n && blockIdx.x > 0) data[i] += blockSums[blockIdx.x];
}

// Scatter (col, val) pairs to row-sorted positions; mutates starts -> ends.
__global__ void k_scatter(const int* __restrict__ rows, const int* __restrict__ cols,
                          const float* __restrict__ vals, int* __restrict__ cursor,
                          int2* __restrict__ pairs, int nnz) {
    int i = blockIdx.x * blockDim.x + threadIdx.x;
    if (i >= nnz) return;
    int r = rows[i];
    int pos = atomicAdd(&cursor[r], 1);
    int2 p;
    p.x = cols[i];
    p.y = __float_as_int(vals[i]);
    pairs[pos] = p;
}

// One wave per row: coalesced pair load + shfl broadcast + FMA, single store.
__global__ void k_spmv(const int2* __restrict__ pairs, const int* __restrict__ ends,
                       const float* __restrict__ weight, const float* __restrict__ bias,
                       float* __restrict__ out, int n) {
    int lane = threadIdx.x & 63;
    int r = blockIdx.x * (blockDim.x >> 6) + (threadIdx.x >> 6);
    if (r >= n) return;
    int start = (r == 0) ? 0 : ends[r - 1];
    int end = ends[r];
    float acc = bias[lane];
    for (int base = start; base < end; base += 64) {
        int len = min(64, end - base);
        int c = 0;
        float v = 0.0f;
        if (lane < len) {
            int2 p = pairs[base + lane];
            c = p.x;
            v = __int_as_float(p.y);
        }
        for (int j = 0; j < len; ++j) {
            int cj = __shfl(c, j);
            float vj = __shfl(v, j);
            acc = fmaf(vj, weight[cj * OUTF + lane], acc);
        }
    }
    out[(long long)r * OUTF + lane] = acc;
}

extern "C" void kernel_launch(void* const* d_in, const int* in_sizes, int n_in,
                              void* d_out, int out_size, void* d_ws, size_t ws_size,
                              hipStream_t stream) {
    const int*   index  = (const int*)d_in[0];
    const float* value  = (const float*)d_in[1];
    const float* weight = (const float*)d_in[3];
    const float* bias   = (const float*)d_in[4];
    float*       out    = (float*)d_out;

    int nnz = in_sizes[0] / 2;
    int n   = out_size / OUTF;
    const int* rows = index;
    const int* cols = index + nnz;

    char* ws = (char*)d_ws;
    int*  cnt       = (int*)ws;                 // n ints (counts -> starts -> ends)
    int*  blockSums = (int*)(ws + (512 << 10)); // <=1024 ints
    int2* pairs     = (int2*)(ws + (1 << 20));  // nnz pairs

    int scanBlocks = (n + SCAN_B - 1) / SCAN_B;  // 196 for n=100000 (<=1024 required)

    k_zero<<<(n + 255) / 256, 256, 0, stream>>>(cnt, n);
    k_hist<<<(nnz + 255) / 256, 256, 0, stream>>>(rows, cnt, nnz);
    k_scan1<<<scanBlocks, SCAN_B, 0, stream>>>(cnt, cnt, blockSums, n);
    k_scan2<<<1, 1024, 0, stream>>>(blockSums, scanBlocks);
    k_scan3<<<scanBlocks, SCAN_B, 0, stream>>>(cnt, blockSums, n);
    k_scatter<<<(nnz + 255) / 256, 256, 0, stream>>>(rows, cols, value, cnt, pairs, nnz);

    int wavesPerBlock = 4;  // 256 threads
    int spmvBlocks = (n + wavesPerBlock - 1) / wavesPerBlock;
    k_spmv<<<spmvBlocks, 256, 0, stream>>>(pairs, cnt, weight, bias, out, n);
}